// Round 1
// baseline (225.628 us; speedup 1.0000x reference)
//
#include <hip/hip_runtime.h>
#include <math.h>

#define HIDDEN 1024
#define NEXP 64
#define ROWS 32      // BIG*INNER rows per expert
#define TOPK 4
#define INNER 8
#define MAXK 3
#define TOTAL 8

// One block per token. 256 threads = 4 waves.
// lane = t & 63 indexes the expert (router) or the row (expert matmuls);
// q = t >> 6 indexes the quarter of the 1024-dim reduction.
__global__ __launch_bounds__(256, 4) void router_fused(
    const float* __restrict__ x,            // [BS, 1024]
    const float* __restrict__ out_gate_w,   // [64, 1024]
    const float* __restrict__ wg,           // [64, 32, 1024]
    const float* __restrict__ wu,           // [64, 32, 1024]
    float* __restrict__ out)                // [BS*8 ids as float][BS*8 weights]
{
    __shared__ __align__(16) float sx[HIDDEN];
    __shared__ float part[4][64];   // [quarter][lane] partial dots (conflict-free layout)
    __shared__ float red[64];       // reduced 64 dots (logits, or 32 gate + 32 up)
    __shared__ int   s_sel[TOPK];
    __shared__ float s_w[TOPK];
    __shared__ float s_scores[ROWS];
    __shared__ int   s_ids[TOTAL];
    __shared__ float s_ws[TOTAL];

    const int b = blockIdx.x;
    const int t = threadIdx.x;
    const int lane = t & 63;
    const int q = t >> 6;

    // ---- stage x row into LDS (256 x float4 = 4 KB) ----
    ((float4*)sx)[t] = ((const float4*)(x + (size_t)b * HIDDEN))[t];
    __syncthreads();

    const float4* x4 = (const float4*)(sx) + q * 64;  // wave-uniform → LDS broadcast reads

    // ---- router logits: lane = expert, q = quarter of dim ----
    {
        const float4* w4 = (const float4*)(out_gate_w + (size_t)lane * HIDDEN) + q * 64;
        float4 acc = {0.f, 0.f, 0.f, 0.f};
        #pragma unroll 8
        for (int i = 0; i < 64; ++i) {
            float4 a = w4[i], bb = x4[i];
            acc.x += a.x * bb.x; acc.y += a.y * bb.y;
            acc.z += a.z * bb.z; acc.w += a.w * bb.w;
        }
        part[q][lane] = (acc.x + acc.y) + (acc.z + acc.w);
    }
    __syncthreads();
    if (t < 64) red[t] = part[0][t] + part[1][t] + part[2][t] + part[3][t];
    __syncthreads();

    // ---- top-4 + renormalized softmax weights (denominator cancels) ----
    if (t == 0) {
        float vals[TOPK];
        for (int k = 0; k < TOPK; ++k) {
            float best = -INFINITY; int bi = 0;
            for (int e = 0; e < NEXP; ++e) {
                float v = red[e];
                if (v > best) { best = v; bi = e; }   // ties -> lowest index, matches jax top_k
            }
            red[bi] = -INFINITY;
            s_sel[k] = bi; vals[k] = best;
        }
        const float m = vals[0];
        float ex[TOPK], s = 0.f;
        for (int k = 0; k < TOPK; ++k) { ex[k] = expf(vals[k] - m); s += ex[k]; }
        const float inv = 1.f / s;
        for (int k = 0; k < TOPK; ++k) s_w[k] = ex[k] * inv;
    }
    __syncthreads();

    const int pat_k[TOPK]   = {3, 2, 2, 1};
    const int pat_off[TOPK] = {0, 3, 5, 7};

    // ---- 4 selected experts: gate/up projections, scores, inner top-k ----
    for (int slot = 0; slot < TOPK; ++slot) {
        const int e = s_sel[slot];
        const float* wbase = (lane < 32)
            ? (wg + ((size_t)e * ROWS + lane) * HIDDEN)
            : (wu + ((size_t)e * ROWS + (lane - 32)) * HIDDEN);
        const float4* w4 = (const float4*)wbase + q * 64;
        float4 acc = {0.f, 0.f, 0.f, 0.f};
        #pragma unroll 8
        for (int i = 0; i < 64; ++i) {
            float4 a = w4[i], bb = x4[i];
            acc.x += a.x * bb.x; acc.y += a.y * bb.y;
            acc.z += a.z * bb.z; acc.w += a.w * bb.w;
        }
        part[q][lane] = (acc.x + acc.y) + (acc.z + acc.w);
        __syncthreads();
        if (t < 64) red[t] = part[0][t] + part[1][t] + part[2][t] + part[3][t];
        __syncthreads();
        if (t < 32) {
            float g = red[t], u = red[t + 32];
            float sig = 1.f / (1.f + expf(-g));
            s_scores[t] = fabsf(u * g * sig);     // |up * silu(gate)|
        }
        __syncthreads();
        if (t == 0) {
            float inner[INNER];
            #pragma unroll
            for (int i = 0; i < INNER; ++i)
                inner[i] = 0.25f * (s_scores[4*i] + s_scores[4*i+1]
                                  + s_scores[4*i+2] + s_scores[4*i+3]);
            const int kk = pat_k[slot], off = pat_off[slot];
            for (int k = 0; k < kk; ++k) {
                float best = -INFINITY; int bi = 0;
                #pragma unroll
                for (int i = 0; i < INNER; ++i)
                    if (inner[i] > best) { best = inner[i]; bi = i; }  // ties -> lowest index
                inner[bi] = -INFINITY;
                s_ids[off + k] = e * INNER + bi;
                s_ws[off + k]  = s_w[slot];       // weights already descending by slot
            }
        }
        __syncthreads();
    }

    // ---- epilogue: sort 8 ids descending; weights already descending ----
    if (t == 0) {
        int ids[TOTAL];
        #pragma unroll
        for (int i = 0; i < TOTAL; ++i) ids[i] = s_ids[i];
        for (int i = 1; i < TOTAL; ++i) {           // insertion sort, descending
            int v = ids[i]; int j = i - 1;
            while (j >= 0 && ids[j] < v) { ids[j+1] = ids[j]; --j; }
            ids[j+1] = v;
        }
        float* oid = out + (size_t)b * TOTAL;
        float* ow  = out + (size_t)gridDim.x * TOTAL + (size_t)b * TOTAL;
        #pragma unroll
        for (int i = 0; i < TOTAL; ++i) {
            oid[i] = (float)ids[i];
            ow[i]  = s_ws[i];
        }
    }
}

extern "C" void kernel_launch(void* const* d_in, const int* in_sizes, int n_in,
                              void* d_out, int out_size, void* d_ws, size_t ws_size,
                              hipStream_t stream) {
    const float* x  = (const float*)d_in[0];
    const float* gw = (const float*)d_in[1];
    const float* wg = (const float*)d_in[2];
    const float* wu = (const float*)d_in[3];
    float* out = (float*)d_out;
    const int bs = in_sizes[0] / HIDDEN;   // 1024

    hipLaunchKernelGGL(router_fused, dim3(bs), dim3(256), 0, stream,
                       x, gw, wg, wu, out);
}

// Round 3
// 191.532 us; speedup vs baseline: 1.1780x; 1.1780x over previous
//
#include <hip/hip_runtime.h>
#include <math.h>

#define HIDDEN 1024
#define NEXP 64
#define ROWS 32
#define TOPK 4
#define INNER 8
#define TOTAL 8
#define TB1 8      // tokens per block, phase 1
#define G  16      // tokens per (expert,chunk) block, phase 2
#define MAXCH 64   // max chunks per expert = 1024/G

// ---------------- phase 1: router + scatter ----------------
__global__ __launch_bounds__(256) void p1_router(
    const float* __restrict__ x, const float* __restrict__ rw,
    int* __restrict__ count, int* __restrict__ tok_list,
    float* __restrict__ w_arr)
{
    __shared__ float part[4][TB1][64];   // [quarter][tok][expert]
    __shared__ float red[TB1][64];

    const int t = threadIdx.x, lane = t & 63, q = t >> 6;
    const int tok0 = blockIdx.x * TB1;

    const float4* w4 = (const float4*)(rw + (size_t)lane * HIDDEN) + q * 64;
    const float4* xbase = (const float4*)(x + (size_t)tok0 * HIDDEN) + q * 64;

    float acc[TB1];
    #pragma unroll
    for (int tok = 0; tok < TB1; ++tok) acc[tok] = 0.f;

    for (int ch = 0; ch < 64; ch += 8) {
        float4 wf[8];
        #pragma unroll
        for (int j = 0; j < 8; ++j) wf[j] = w4[ch + j];
        #pragma unroll
        for (int tok = 0; tok < TB1; ++tok) {
            const float4* xx = xbase + tok * 256 + ch;   // wave-uniform -> broadcast
            float4 s = {0.f, 0.f, 0.f, 0.f};
            #pragma unroll
            for (int j = 0; j < 8; ++j) {
                float4 b = xx[j];
                s.x += wf[j].x * b.x; s.y += wf[j].y * b.y;
                s.z += wf[j].z * b.z; s.w += wf[j].w * b.w;
            }
            acc[tok] += (s.x + s.y) + (s.z + s.w);
        }
    }
    #pragma unroll
    for (int tok = 0; tok < TB1; ++tok) part[q][tok][lane] = acc[tok];
    __syncthreads();

    for (int i = t; i < TB1 * 64; i += 256) {
        int tok = i >> 6, e = i & 63;
        red[tok][e] = part[0][tok][e] + part[1][tok][e]
                    + part[2][tok][e] + part[3][tok][e];
    }
    __syncthreads();

    if (t < TB1) {
        const int token = tok0 + t;
        float vals[TOPK]; int sel[TOPK];
        for (int k = 0; k < TOPK; ++k) {
            float best = -INFINITY; int bi = 0;
            for (int e = 0; e < NEXP; ++e) {
                float v = red[t][e];
                if (v > best) { best = v; bi = e; }   // ties -> lowest index
            }
            red[t][bi] = -INFINITY;
            sel[k] = bi; vals[k] = best;
        }
        const float m = vals[0];
        float ex[TOPK], s = 0.f;
        for (int k = 0; k < TOPK; ++k) { ex[k] = expf(vals[k] - m); s += ex[k]; }
        const float inv = 1.f / s;
        for (int k = 0; k < TOPK; ++k) {
            w_arr[token * TOPK + k] = ex[k] * inv;
            int pos = atomicAdd(&count[sel[k]], 1);       // device-scope
            tok_list[sel[k] * 1024 + pos] = (token << 2) | k;
        }
    }
}

// ---------------- phase 2: expert matmuls + inner top-k ----------------
__global__ __launch_bounds__(256) void p2_experts(
    const float* __restrict__ x,
    const float* __restrict__ wg, const float* __restrict__ wu,
    const int* __restrict__ count, const int* __restrict__ tok_list,
    int* __restrict__ ids_buf)
{
    __shared__ float part[4][G][64];     // [quarter][tok][row] 16 KB, conflict-free
    __shared__ float sscore[G][32];
    __shared__ int   s_entry[G];

    const int e = blockIdx.x, c = blockIdx.y;
    const int n = count[e];
    const int i0 = c * G;
    if (i0 >= n) return;
    const int T = (n - i0 < G) ? (n - i0) : G;

    const int t = threadIdx.x, lane = t & 63, q = t >> 6;

    if (t < G)
        s_entry[t] = tok_list[e * 1024 + i0 + ((t < T) ? t : 0)];  // clamp invalid -> entry 0
    __syncthreads();

    const float* wrow = (lane < 32)
        ? wg + ((size_t)e * ROWS + lane) * HIDDEN
        : wu + ((size_t)e * ROWS + (lane - 32)) * HIDDEN;
    const float4* w4 = (const float4*)wrow + q * 64;

    const float4* xp[G];
    #pragma unroll
    for (int tok = 0; tok < G; ++tok)
        xp[tok] = (const float4*)(x + (size_t)(s_entry[tok] >> 2) * HIDDEN) + q * 64;

    float acc[G];
    #pragma unroll
    for (int tok = 0; tok < G; ++tok) acc[tok] = 0.f;

    for (int ch = 0; ch < 64; ch += 8) {
        float4 wf[8];                                   // weights reused across G tokens
        #pragma unroll
        for (int j = 0; j < 8; ++j) wf[j] = w4[ch + j];
        #pragma unroll
        for (int tok = 0; tok < G; ++tok) {
            const float4* xx = xp[tok] + ch;            // wave-uniform broadcast reads
            float4 s = {0.f, 0.f, 0.f, 0.f};
            #pragma unroll
            for (int j = 0; j < 8; ++j) {
                float4 b = xx[j];
                s.x += wf[j].x * b.x; s.y += wf[j].y * b.y;
                s.z += wf[j].z * b.z; s.w += wf[j].w * b.w;
            }
            acc[tok] += (s.x + s.y) + (s.z + s.w);
        }
    }
    #pragma unroll
    for (int tok = 0; tok < G; ++tok) part[q][tok][lane] = acc[tok];
    __syncthreads();

    for (int i = t; i < 32 * G; i += 256) {
        const int tok = i >> 5, r = i & 31;
        float g = 0.f, u = 0.f;
        #pragma unroll
        for (int qq = 0; qq < 4; ++qq) { g += part[qq][tok][r]; u += part[qq][tok][r + 32]; }
        const float sil = g / (1.f + expf(-g));
        sscore[tok][r] = fabsf(u * sil);
    }
    __syncthreads();

    if (t < T) {
        const int entry = s_entry[t], token = entry >> 2, slot = entry & 3;
        float inner[INNER];
        #pragma unroll
        for (int i = 0; i < INNER; ++i)
            inner[i] = 0.25f * (sscore[t][4*i] + sscore[t][4*i+1]
                              + sscore[t][4*i+2] + sscore[t][4*i+3]);
        const int kk  = (slot == 0) ? 3 : ((slot == 3) ? 1 : 2);
        const int off = (slot == 0) ? 0 : ((slot == 1) ? 3 : ((slot == 2) ? 5 : 7));
        for (int k = 0; k < kk; ++k) {
            float best = -INFINITY; int bi = 0;
            #pragma unroll
            for (int i = 0; i < INNER; ++i)
                if (inner[i] > best) { best = inner[i]; bi = i; }
            inner[bi] = -INFINITY;
            ids_buf[token * TOTAL + off + k] = e * INNER + bi;
        }
    }
}

// ---------------- phase 3: assemble outputs ----------------
__global__ __launch_bounds__(256) void p3_assemble(
    const int* __restrict__ ids_buf, const float* __restrict__ w_arr,
    float* __restrict__ out, int bs)
{
    const int token = blockIdx.x * 256 + threadIdx.x;
    if (token >= bs) return;

    int ids[TOTAL];
    #pragma unroll
    for (int i = 0; i < TOTAL; ++i) ids[i] = ids_buf[token * TOTAL + i];
    for (int i = 1; i < TOTAL; ++i) {            // insertion sort, descending
        int v = ids[i]; int j = i - 1;
        while (j >= 0 && ids[j] < v) { ids[j+1] = ids[j]; --j; }
        ids[j+1] = v;
    }
    const float w0 = w_arr[token*4+0], w1 = w_arr[token*4+1];
    const float w2 = w_arr[token*4+2], w3 = w_arr[token*4+3];
    const float ws[TOTAL] = {w0, w0, w0, w1, w1, w2, w2, w3};  // already descending

    float* oid = out + (size_t)token * TOTAL;
    float* ow  = out + (size_t)bs * TOTAL + (size_t)token * TOTAL;
    #pragma unroll
    for (int i = 0; i < TOTAL; ++i) { oid[i] = (float)ids[i]; ow[i] = ws[i]; }
}

extern "C" void kernel_launch(void* const* d_in, const int* in_sizes, int n_in,
                              void* d_out, int out_size, void* d_ws, size_t ws_size,
                              hipStream_t stream) {
    const float* x  = (const float*)d_in[0];
    const float* rw = (const float*)d_in[1];
    const float* wg = (const float*)d_in[2];
    const float* wu = (const float*)d_in[3];
    float* out = (float*)d_out;
    const int bs = in_sizes[0] / HIDDEN;   // 1024

    // workspace layout (ints/floats): count[64] | tok_list[64*1024] | w_arr[bs*4] | ids_buf[bs*8]
    int*   count    = (int*)d_ws;
    int*   tok_list = count + 64;
    float* w_arr    = (float*)(tok_list + 64 * 1024);
    int*   ids_buf  = (int*)(w_arr + (size_t)bs * TOPK);

    hipMemsetAsync(count, 0, 64 * sizeof(int), stream);
    hipLaunchKernelGGL(p1_router, dim3(bs / TB1), dim3(256), 0, stream,
                       x, rw, count, tok_list, w_arr);
    hipLaunchKernelGGL(p2_experts, dim3(NEXP, MAXCH), dim3(256), 0, stream,
                       x, wg, wu, count, tok_list, ids_buf);
    hipLaunchKernelGGL(p3_assemble, dim3((bs + 255) / 256), dim3(256), 0, stream,
                       ids_buf, w_arr, out, bs);
}

// Round 4
// 135.557 us; speedup vs baseline: 1.6645x; 1.4129x over previous
//
#include <hip/hip_runtime.h>
#include <math.h>

#define HIDDEN 1024
#define NEXP 64
#define ROWS 32
#define TOPK 4
#define INNER 8
#define TOTAL 8
#define TB1 2      // tokens per block, phase 1  (512 blocks -> 2/CU)
#define G 4        // pairs per block, phase 2   (~1056 working blocks -> 4/CU)
#define MAXCH 128  // chunks per expert covered: G*MAXCH=512 >= 58 sigma of count

// ---------------- phase 1: router + scatter ----------------
// wave w handles experts [16w,16w+16); 4 lanes per expert row (j=lane&3 takes
// chunk j+4k -> each wave instr reads 16 fully-used 64B lines, coalesced).
__global__ __launch_bounds__(256) void p1_router(
    const float* __restrict__ x, const float* __restrict__ rw,
    int* __restrict__ count, int* __restrict__ tok_list,
    float* __restrict__ w_arr)
{
    __shared__ __align__(16) float sx[TB1][HIDDEN];   // 8 KB
    __shared__ float red[NEXP][TB1];

    const int t = threadIdx.x, lane = t & 63, w = t >> 6;
    const int j = lane & 3, r = lane >> 2;
    const int E = w * 16 + r;
    const int tok0 = blockIdx.x * TB1;

    {   // stage TB1 x rows, coalesced
        const float4* src = (const float4*)(x + (size_t)tok0 * HIDDEN);
        float4* dst = (float4*)sx;
        dst[t] = src[t];
        dst[t + 256] = src[t + 256];
    }
    __syncthreads();

    const float4* w4  = (const float4*)(rw + (size_t)E * HIDDEN);
    const float4* x40 = (const float4*)sx[0];
    const float4* x41 = (const float4*)sx[1];

    float a0 = 0.f, a1 = 0.f;
    #pragma unroll 8
    for (int k = 0; k < 64; ++k) {
        const int c = j + 4 * k;
        float4 wv = w4[c];
        float4 b0 = x40[c], b1 = x41[c];          // broadcast ds_read, conflict-free
        a0 += wv.x*b0.x + wv.y*b0.y + wv.z*b0.z + wv.w*b0.w;
        a1 += wv.x*b1.x + wv.y*b1.y + wv.z*b1.z + wv.w*b1.w;
    }
    a0 += __shfl_xor(a0, 1); a0 += __shfl_xor(a0, 2);
    a1 += __shfl_xor(a1, 1); a1 += __shfl_xor(a1, 2);
    if (j == 0) { red[E][0] = a0; red[E][1] = a1; }
    __syncthreads();

    if (t < TB1) {
        const int token = tok0 + t;
        float vals[TOPK]; int sel[TOPK];
        for (int k = 0; k < TOPK; ++k) {
            float best = -INFINITY; int bi = 0;
            for (int e = 0; e < NEXP; ++e) {
                float v = red[e][t];
                if (v > best) { best = v; bi = e; }   // ties -> lowest index
            }
            red[sel[k] = bi][t] = -INFINITY;
            vals[k] = best;
        }
        const float m = vals[0];
        float ex[TOPK], s = 0.f;
        for (int k = 0; k < TOPK; ++k) { ex[k] = expf(vals[k] - m); s += ex[k]; }
        const float inv = 1.f / s;
        for (int k = 0; k < TOPK; ++k) {
            w_arr[token * TOPK + k] = ex[k] * inv;
            int pos = atomicAdd(&count[sel[k]], 1);
            tok_list[sel[k] * 1024 + pos] = (token << 2) | k;
        }
    }
}

// ---------------- phase 2: expert matmuls + inner top-k ----------------
// wave w handles rows [16w,16w+16) of the 64 (32 gate + 32 up); 4 lanes/row.
__global__ __launch_bounds__(256) void p2_experts(
    const float* __restrict__ x,
    const float* __restrict__ wg, const float* __restrict__ wu,
    const int* __restrict__ count, const int* __restrict__ tok_list,
    int* __restrict__ ids_buf)
{
    __shared__ __align__(16) float sx[G][HIDDEN];   // 16 KB
    __shared__ __align__(16) float sred[64][G];     // 1 KB
    __shared__ float sscore[G][ROWS];
    __shared__ int   s_entry[G];

    const int e = blockIdx.x, c0 = blockIdx.y;
    const int n = count[e];
    const int i0 = c0 * G;
    if (i0 >= n) return;
    const int T = (n - i0 < G) ? (n - i0) : G;

    const int t = threadIdx.x, lane = t & 63, w = t >> 6;
    const int j = lane & 3, r = lane >> 2;
    const int R = w * 16 + r;   // 0..63: gate rows 0..31, up rows 32..63

    if (t < G)
        s_entry[t] = tok_list[e * 1024 + i0 + ((t < T) ? t : 0)];
    __syncthreads();

    {   // stage G token rows, coalesced (16 B/lane)
        float4* dst = (float4*)sx;
        #pragma unroll
        for (int i = 0; i < G; ++i)
            dst[256 * i + t] =
                ((const float4*)(x + (size_t)(s_entry[i] >> 2) * HIDDEN))[t];
    }
    __syncthreads();

    const float* wrow = (R < 32)
        ? wg + ((size_t)e * ROWS + R) * HIDDEN
        : wu + ((size_t)e * ROWS + (R - 32)) * HIDDEN;
    const float4* w4 = (const float4*)wrow;

    float acc[G] = {0.f, 0.f, 0.f, 0.f};
    #pragma unroll 8
    for (int k = 0; k < 64; ++k) {
        const int c = j + 4 * k;
        float4 wv = w4[c];                       // 16 lines/instr, fully consumed
        #pragma unroll
        for (int tok = 0; tok < G; ++tok) {
            float4 b = ((const float4*)sx[tok])[c];   // broadcast, conflict-free
            acc[tok] += wv.x*b.x + wv.y*b.y + wv.z*b.z + wv.w*b.w;
        }
    }
    #pragma unroll
    for (int tok = 0; tok < G; ++tok) {
        acc[tok] += __shfl_xor(acc[tok], 1);
        acc[tok] += __shfl_xor(acc[tok], 2);
    }
    if (j == 0) {
        float4 v; v.x = acc[0]; v.y = acc[1]; v.z = acc[2]; v.w = acc[3];
        *((float4*)sred[R]) = v;
    }
    __syncthreads();

    if (t < 32 * G) {
        const int tok = t >> 5, rr = t & 31;
        const float g = sred[rr][tok], u = sred[rr + 32][tok];
        sscore[tok][rr] = fabsf(u * (g / (1.f + expf(-g))));
    }
    __syncthreads();

    if (t < T) {
        const int entry = s_entry[t], token = entry >> 2, slot = entry & 3;
        float inner[INNER];
        #pragma unroll
        for (int i = 0; i < INNER; ++i)
            inner[i] = 0.25f * (sscore[t][4*i] + sscore[t][4*i+1]
                              + sscore[t][4*i+2] + sscore[t][4*i+3]);
        const int kk  = (slot == 0) ? 3 : ((slot == 3) ? 1 : 2);
        const int off = (slot == 0) ? 0 : ((slot == 1) ? 3 : ((slot == 2) ? 5 : 7));
        for (int k = 0; k < kk; ++k) {
            float best = -INFINITY; int bi = 0;
            #pragma unroll
            for (int i = 0; i < INNER; ++i)
                if (inner[i] > best) { best = inner[i]; bi = i; }
            inner[bi] = -INFINITY;
            ids_buf[token * TOTAL + off + k] = e * INNER + bi;
        }
    }
}

// ---------------- phase 3: assemble outputs ----------------
__global__ __launch_bounds__(256) void p3_assemble(
    const int* __restrict__ ids_buf, const float* __restrict__ w_arr,
    float* __restrict__ out, int bs)
{
    const int token = blockIdx.x * 256 + threadIdx.x;
    if (token >= bs) return;

    int ids[TOTAL];
    #pragma unroll
    for (int i = 0; i < TOTAL; ++i) ids[i] = ids_buf[token * TOTAL + i];
    for (int i = 1; i < TOTAL; ++i) {            // insertion sort, descending
        int v = ids[i]; int j = i - 1;
        while (j >= 0 && ids[j] < v) { ids[j+1] = ids[j]; --j; }
        ids[j+1] = v;
    }
    const float w0 = w_arr[token*4+0], w1 = w_arr[token*4+1];
    const float w2 = w_arr[token*4+2], w3 = w_arr[token*4+3];
    const float ws[TOTAL] = {w0, w0, w0, w1, w1, w2, w2, w3};  // already descending

    float* oid = out + (size_t)token * TOTAL;
    float* ow  = out + (size_t)bs * TOTAL + (size_t)token * TOTAL;
    #pragma unroll
    for (int i = 0; i < TOTAL; ++i) { oid[i] = (float)ids[i]; ow[i] = ws[i]; }
}

extern "C" void kernel_launch(void* const* d_in, const int* in_sizes, int n_in,
                              void* d_out, int out_size, void* d_ws, size_t ws_size,
                              hipStream_t stream) {
    const float* x  = (const float*)d_in[0];
    const float* rw = (const float*)d_in[1];
    const float* wg = (const float*)d_in[2];
    const float* wu = (const float*)d_in[3];
    float* out = (float*)d_out;
    const int bs = in_sizes[0] / HIDDEN;   // 1024

    // workspace: count[64] | tok_list[64*1024] | w_arr[bs*4] | ids_buf[bs*8]
    int*   count    = (int*)d_ws;
    int*   tok_list = count + 64;
    float* w_arr    = (float*)(tok_list + 64 * 1024);
    int*   ids_buf  = (int*)(w_arr + (size_t)bs * TOPK);

    hipMemsetAsync(count, 0, 64 * sizeof(int), stream);
    hipLaunchKernelGGL(p1_router, dim3(bs / TB1), dim3(256), 0, stream,
                       x, rw, count, tok_list, w_arr);
    hipLaunchKernelGGL(p2_experts, dim3(NEXP, MAXCH), dim3(256), 0, stream,
                       x, wg, wu, count, tok_list, ids_buf);
    hipLaunchKernelGGL(p3_assemble, dim3((bs + 255) / 256), dim3(256), 0, stream,
                       ids_buf, w_arr, out, bs);
}